// Round 6
// baseline (6379.873 us; speedup 1.0000x reference)
//
#include <hip/hip_runtime.h>

#define DEV __device__ __forceinline__

// ---- repetition macros (25-wide) ----
#define RA(F) F(0) F(1) F(2) F(3) F(4) F(5) F(6) F(7) F(8) F(9) F(10) F(11) \
  F(12) F(13) F(14) F(15) F(16) F(17) F(18) F(19) F(20) F(21) F(22) F(23) F(24)
#define RB(F,j) F(j,0) F(j,1) F(j,2) F(j,3) F(j,4) F(j,5) F(j,6) F(j,7) F(j,8) \
  F(j,9) F(j,10) F(j,11) F(j,12) F(j,13) F(j,14) F(j,15) F(j,16) F(j,17) \
  F(j,18) F(j,19) F(j,20) F(j,21) F(j,22) F(j,23) F(j,24)
#define AP8(F) F(0) F(1) F(2) F(3) F(4) F(5) F(6) F(7)

namespace {

constexpr int B_ = 8;
constexpr int N_ = 1024;
constexpr int M_ = 256;
constexpr int D_ = 25;
constexpr int FH_ = 240;
constexpr int NATOM = B_ * N_;          // 8192
constexpr float CSC = 1.0f / 256.0f;    // 4/(NN*NTYPES*4)
constexpr int WROW = 28;                // LDS weight row pad: 112B, 16B-aligned

DEV float fast_tanh(float x) {
  float ax = fabsf(x);
  float e = __expf(-2.0f * ax);
  float r = (1.0f - e) * __builtin_amdgcn_rcpf(1.0f + e);
  return copysignf(r, x);
}

// Normalized descriptor channels (pure scalars — no arrays, SROA-safe).
DEV void geom_blk(float dx, float dy, float dz, int nb, int t, int m,
                  const float* __restrict__ davg, const float* __restrict__ dstd,
                  float& o0, float& o1, float& o2, float& o3) {
  float mf = (nb > 0) ? 1.0f : 0.0f;
  float dr2 = dx * dx + dy * dy + dz * dz;
  float safe = (nb > 0) ? dr2 : 1.0f;
  float rs = __builtin_amdgcn_rsqf(safe);
  float rij = safe * rs;
  float inr = mf * rs;
  float x = rij * mf;
  float inr2 = inr * inr;
  float u = (x - 5.8f) * 5.0f;
  float uu = u * u;
  float A = -6.0f * uu + 15.0f * u - 10.0f;
  float poly = uu * u * A + 1.0f;
  bool mid = (x >= 5.8f) && (x < 6.0f);
  float vv = ((x < 5.8f) ? 1.0f : (mid ? poly : 0.0f)) * mf;
  int bidx = (t * M_ + m) * 4;
  float4 av = *(const float4*)(davg + bidx);
  float4 sv = *(const float4*)(dstd + bidx);
  o0 = (inr * vv - av.x) * __builtin_amdgcn_rcpf(sv.x);
  o1 = (dx * inr2 * vv - av.y) * __builtin_amdgcn_rcpf(sv.y);
  o2 = (dy * inr2 * vv - av.z) * __builtin_amdgcn_rcpf(sv.z);
  o3 = (dz * inr2 * vv - av.w) * __builtin_amdgcn_rcpf(sv.w);
}

// Jacobian folded straight into the force projection (no rid[12] array).
DEV void geom_force(float dx, float dy, float dz, int nb, int t, int m,
                    const float* __restrict__ dstd,
                    float dE0, float dE1, float dE2, float dE3,
                    float& px, float& py, float& pz) {
  float mf = (nb > 0) ? 1.0f : 0.0f;
  float dr2 = dx * dx + dy * dy + dz * dz;
  float safe = (nb > 0) ? dr2 : 1.0f;
  float rs = __builtin_amdgcn_rsqf(safe);
  float rij = safe * rs;
  float inr = mf * rs;
  float x = rij * mf;
  float inr2 = inr * inr;
  float inr4 = inr2 * inr2;
  float inr3 = inr4 * x;
  float u = (x - 5.8f) * 5.0f;
  float uu = u * u;
  float A = -6.0f * uu + 15.0f * u - 10.0f;
  float poly = uu * u * A + 1.0f;
  float dpoly = (3.0f * uu * A + uu * u * (-12.0f * u + 15.0f)) * 5.0f;
  bool mid = (x >= 5.8f) && (x < 6.0f);
  float vv = ((x < 5.8f) ? 1.0f : (mid ? poly : 0.0f)) * mf;
  float dvv = (mid ? dpoly : 0.0f) * mf;
  int bidx = (t * M_ + m) * 4;
  float4 sv = *(const float4*)(dstd + bidx);
  float e0 = dE0 * mf * __builtin_amdgcn_rcpf(sv.x);
  float e1 = dE1 * mf * __builtin_amdgcn_rcpf(sv.y);
  float e2 = dE2 * mf * __builtin_amdgcn_rcpf(sv.z);
  float e3 = dE3 * mf * __builtin_amdgcn_rcpf(sv.w);
  float ci = dvv * inr;
  float comx = ci * dx, comy = ci * dy, comz = ci * dz;
  float iv = inr3 * vv;
  float pre0 = inr, pre1 = dx * inr2, pre2 = dy * inr2, pre3 = dz * inr2;
  float txx = 2.0f * dx * dx * inr4 - inr2;
  float tyy = 2.0f * dy * dy * inr4 - inr2;
  float tzz = 2.0f * dz * dz * inr4 - inr2;
  float txy = 2.0f * dx * dy * inr4;
  float txz = 2.0f * dx * dz * inr4;
  float tyz = 2.0f * dy * dz * inr4;
  px = e0 * (dx * iv - pre0 * comx) + e1 * (txx * vv - pre1 * comx) +
       e2 * (txy * vv - pre2 * comx) + e3 * (txz * vv - pre3 * comx);
  py = e0 * (dy * iv - pre0 * comy) + e1 * (txy * vv - pre1 * comy) +
       e2 * (tyy * vv - pre2 * comy) + e3 * (tyz * vv - pre3 * comy);
  pz = e0 * (dz * iv - pre0 * comz) + e1 * (txz * vv - pre1 * comz) +
       e2 * (tyz * vv - pre2 * comz) + e3 * (tzz * vv - pre3 * comz);
}

// Cooperative staging of this type's two embedding-weight pairs into LDS.
// Rows padded to WROW so ds_read_b128 stays 16B-aligned. Uniform-address
// ds_reads broadcast conflict-free.
DEV void stage_weights(int t, int m,
                       const float* __restrict__ eW0, const float* __restrict__ eb0,
                       const float* __restrict__ eW1, const float* __restrict__ eb1,
                       const float* __restrict__ eW2, const float* __restrict__ eb2,
                       float (*sW1)[D_ * WROW], float (*sW2)[D_ * WROW],
                       float (*sWb)[4 * WROW]) {
  for (int idx = m; idx < 2 * 625; idx += 256) {
    int h = idx / 625;
    int r = idx - h * 625;
    int pp = t * 2 + h;
    int f = r / 25, e = r - f * 25;
    sW1[h][f * WROW + e] = eW1[pp * 625 + r];
    sW2[h][f * WROW + e] = eW2[pp * 625 + r];
  }
  if (m < 50) {
    int h = m / 25, e = m - h * 25;
    int pp = t * 2 + h;
    sWb[h][0 * WROW + e] = eW0[pp * 25 + e];
    sWb[h][1 * WROW + e] = eb0[pp * 25 + e];
    sWb[h][2 * WROW + e] = eb1[pp * 25 + e];
    sWb[h][3 * WROW + e] = eb2[pp * 25 + e];
  }
}

// ---- K1 macro bodies: embedding forward, all named scalars, LDS weights ----
#define K1H0(e) float h##e = fast_tanh(fmaf(s0, W0p[e], b0p[e]));
#define K1A1(e) float a##e = b1p[e];
#define K1M1E(f,e) a##e = fmaf(hf, W1p[(f)*WROW+(e)], a##e);
#define K1M1R(f) { const float hf = h##f; RB(K1M1E, f) }
#define K1H1(e) h##e += fast_tanh(a##e);
#define K1A2(e) a##e = b2p[e];
#define K1M2E(f,e) a##e = fmaf(hf, W2p[(f)*WROW+(e)], a##e);
#define K1M2R(f) { const float hf = h##f; RB(K1M2E, f) }
#define K1ST(e) sGT[e][m] = h##e + fast_tanh(a##e);

// K1: per atom (block) x neighbor (thread): geometry + embed fwd, then
// acc[4][25] via transposed-LDS float4 reduction.
__global__ __launch_bounds__(256, 3) void k_embed_acc(
    const float* __restrict__ dR, const int* __restrict__ neigh,
    const float* __restrict__ davg, const float* __restrict__ dstd,
    const float* __restrict__ eW0, const float* __restrict__ eb0,
    const float* __restrict__ eW1, const float* __restrict__ eb1,
    const float* __restrict__ eW2, const float* __restrict__ eb2,
    float* __restrict__ acc_ws) {
  __shared__ float sW1[2][D_ * WROW];
  __shared__ float sW2[2][D_ * WROW];
  __shared__ float sWb[2][4 * WROW];
  __shared__ float sGT[D_][260];   // row stride 260 floats: rows 16B-aligned
  __shared__ float sBT[4][260];
  int atom = blockIdx.x;
  int n = atom & (N_ - 1);
  int t = (n >= 512) ? 1 : 0;
  int m = threadIdx.x;
  stage_weights(t, m, eW0, eb0, eW1, eb1, eW2, eb2, sW1, sW2, sWb);
  int base = atom * M_ + m;
  float dx = dR[base * 3 + 0];
  float dy = dR[base * 3 + 1];
  float dz = dR[base * 3 + 2];
  int nb = neigh[base];
  float bb0, bb1, bb2, bb3;
  geom_blk(dx, dy, dz, nb, t, m, davg, dstd, bb0, bb1, bb2, bb3);
  __syncthreads();
  int half = m >> 7;
  const float* W1p = &sW1[half][0];
  const float* W2p = &sW2[half][0];
  const float* W0p = &sWb[half][0];
  const float* b0p = W0p + WROW;
  const float* b1p = W0p + 2 * WROW;
  const float* b2p = W0p + 3 * WROW;
  float s0 = bb0;
  RA(K1H0)
  RA(K1A1)
  RA(K1M1R)
  RA(K1H1)
  RA(K1A2)
  RA(K1M2R)
  RA(K1ST)
  sBT[0][m] = bb0; sBT[1][m] = bb1; sBT[2][m] = bb2; sBT[3][m] = bb3;
  __syncthreads();
  if (threadIdx.x < 100) {
    int e = threadIdx.x >> 2;
    int d = threadIdx.x & 3;
    const float4* g4 = (const float4*)(&sGT[e][0]);
    const float4* b4 = (const float4*)(&sBT[d][0]);
    float sum = 0.0f;
    for (int k = 0; k < 64; ++k) {
      float4 g = g4[k];
      float4 b = b4[k];
      sum += b.x * g.x + b.y * g.y + b.z * g.z + b.w * g.w;
    }
    acc_ws[atom * 100 + d * D_ + e] = sum * CSC;
  }
}

// ---- K2 macro bodies: 8 named accumulators ----
#define DECL8(v) float c0=(v),c1=(v),c2=(v),c3=(v),c4=(v),c5=(v),c6=(v),c7=(v);
#define F8X(q)  c##q = fmaf(sX[q][i], w, c##q);
#define F8H0(q) c##q = fmaf(sH0[q][f], w, c##q);
#define F8H1(q) c##q = fmaf(sH1[q][f], w, c##q);
#define F8T2(q) c##q = fmaf(sT2[q][k], w, c##q);
#define F8T1(q) c##q = fmaf(sT1[q][k], w, c##q);
#define F8G0(q) c##q = fmaf(sH0[q][jj], w, c##q);
#define L0S(q) sH0[q][j] = fast_tanh(c##q);
#define L1S(q) { float tv = fast_tanh(c##q); sT1[q][j] = tv; sH1[q][j] = sH0[q][j] + tv; }
#define L2S(q) { float tv = fast_tanh(c##q); sT2[q][j] = tv; atomicAdd(&sEi[q], (sH1[q][j] + tv) * w3); }
#define G2S(q) { float tv = sT2[q][j]; sT2[q][j] = w3 * (1.0f - tv * tv); }
#define D1S(q) { float dh1 = c##q; float tv = sT1[q][j]; sH1[q][j] = dh1; sT1[q][j] = dh1 * (1.0f - tv * tv); }
#define D0S(q) { float h0v = sH0[q][j]; sH0[q][j] = c##q * (1.0f - h0v * h0v); }
#define DXS(q) sX[q][i] = c##q;

// K2: 8 atoms per block. DRt + fitting net fwd + bwd -> Ei/Etot + dacc.
__global__ __launch_bounds__(256, 4) void k_fit(
    const float* __restrict__ acc_ws,
    const float* __restrict__ fW0, const float* __restrict__ fb0,
    const float* __restrict__ fW1, const float* __restrict__ fb1,
    const float* __restrict__ fW2, const float* __restrict__ fb2,
    const float* __restrict__ fW3, const float* __restrict__ fb3,
    const float* __restrict__ ener_shift,
    float* __restrict__ dacc_ws, float* __restrict__ out) {
  constexpr int AB = 8;
  __shared__ float sAcc[AB][100];
  __shared__ float sX[AB][400];
  __shared__ float sH0[AB][FH_];
  __shared__ float sT1[AB][FH_];
  __shared__ float sH1[AB][FH_];
  __shared__ float sT2[AB][FH_];
  __shared__ float sEi[AB];
  int a0 = blockIdx.x * AB;
  int bb = a0 >> 10;
  int n0 = a0 & (N_ - 1);
  int t = (n0 >= 512) ? 1 : 0;
  int tid = threadIdx.x;
  for (int idx = tid; idx < AB * 100; idx += 256)
    ((float*)sAcc)[idx] = acc_ws[a0 * 100 + idx];
  if (tid < AB) sEi[tid] = 0.0f;
  __syncthreads();
  for (int idx = tid; idx < AB * 400; idx += 256) {
    int a = idx / 400; int r = idx % 400; int e = r >> 4; int f = r & 15;
    const float* A = sAcc[a];
    sX[a][r] = A[e] * A[f] + A[25 + e] * A[25 + f] + A[50 + e] * A[50 + f] +
               A[75 + e] * A[75 + f];
  }
  __syncthreads();
  const float* W0 = fW0 + t * 400 * FH_;
  const float* W1 = fW1 + t * FH_ * FH_;
  const float* W2 = fW2 + t * FH_ * FH_;
  const float* B0 = fb0 + t * FH_;
  const float* B1 = fb1 + t * FH_;
  const float* B2 = fb2 + t * FH_;
  const float* W3 = fW3 + t * FH_;
  int j = tid;
  if (j < FH_) {  // layer 0: 400 -> 240
    DECL8(B0[j])
    for (int i = 0; i < 400; ++i) { float w = W0[i * FH_ + j]; AP8(F8X) }
    AP8(L0S)
  }
  __syncthreads();
  if (j < FH_) {  // layer 1 (residual)
    DECL8(B1[j])
    for (int f = 0; f < FH_; ++f) { float w = W1[f * FH_ + j]; AP8(F8H0) }
    AP8(L1S)
  }
  __syncthreads();
  if (j < FH_) {  // layer 2 (residual) + Ei dot
    DECL8(B2[j])
    for (int f = 0; f < FH_; ++f) { float w = W2[f * FH_ + j]; AP8(F8H1) }
    float w3 = W3[j];
    AP8(L2S)
  }
  __syncthreads();
  if (tid < AB) {
    float ei = sEi[tid] + fb3[t] + ener_shift[t];
    out[8 + a0 + tid] = ei;            // Ei
    sEi[tid] = ei;
  }
  if (j < FH_) {  // g2 = W3*(1 - t2^2)
    float w3 = W3[j];
    AP8(G2S)
  }
  __syncthreads();
  if (tid == 0) {
    float s = sEi[0] + sEi[1] + sEi[2] + sEi[3] + sEi[4] + sEi[5] + sEi[6] + sEi[7];
    atomicAdd(&out[bb], s);
  }
  if (j < FH_) {  // dh1 = W3 + g2 @ W2^T ; g1 = dh1*(1-t1^2)
    DECL8(W3[j])
    for (int k = 0; k < FH_; ++k) { float w = W2[j * FH_ + k]; AP8(F8T2) }
    AP8(D1S)
  }
  __syncthreads();
  if (j < FH_) {  // dh0 = dh1 + g1 @ W1^T ; g0 = dh0*(1-h0^2)
    DECL8(sH1[0][j])
    c1 = sH1[1][j]; c2 = sH1[2][j]; c3 = sH1[3][j];
    c4 = sH1[4][j]; c5 = sH1[5][j]; c6 = sH1[6][j]; c7 = sH1[7][j];
    for (int k = 0; k < FH_; ++k) { float w = W1[j * FH_ + k]; AP8(F8T1) }
    AP8(D0S)
  }
  __syncthreads();
  for (int i = tid; i < 400; i += 256) {  // dx = g0 @ W0^T
    DECL8(0.0f)
    for (int jj = 0; jj < FH_; ++jj) { float w = W0[i * FH_ + jj]; AP8(F8G0) }
    AP8(DXS)
  }
  __syncthreads();
  for (int idx = tid; idx < AB * 100; idx += 256) {
    int a = idx / 100; int r = idx % 100; int d = r / 25; int e = r % 25;
    const float* A = sAcc[a];
    const float* DX = sX[a];
    float sum = 0.0f;
#pragma unroll
    for (int f = 0; f < 16; ++f) sum = fmaf(DX[e * 16 + f], A[d * 25 + f], sum);
    if (e < 16) {
#pragma unroll
      for (int e2 = 0; e2 < 25; ++e2) sum = fmaf(DX[e2 * 16 + e], A[d * 25 + e2], sum);
    }
    dacc_ws[a0 * 100 + idx] = sum;
  }
}

// ---- K3 macro bodies: embed fwd + VJP, named scalars, LDS weights ----
#define K3H0(e) float x##e = fast_tanh(fmaf(s0, W0p[e], b0p[e]));
#define K3A1(e) float a##e = b1p[e];
#define K3M1E(f,e) a##e = fmaf(hf, W1p[(f)*WROW+(e)], a##e);
#define K3M1R(f) { const float hf = x##f; RB(K3M1E, f) }
#define K3T1(e) float t##e = fast_tanh(a##e); x##e += t##e;
#define K3A2(e) a##e = b2p[e];
#define K3M2E(f,e) a##e = fmaf(hf, W2p[(f)*WROW+(e)], a##e);
#define K3M2R(f) { const float hf = x##f; RB(K3M2E, f) }
#define K3DY(e) float y##e;
#define K3SD(e) { float t2 = fast_tanh(a##e); float G = x##e + t2; \
  db0 = fmaf(dacp[e], G, db0); db1 = fmaf(dacp[25+(e)], G, db1); \
  db2 = fmaf(dacp[50+(e)], G, db2); db3 = fmaf(dacp[75+(e)], G, db3); \
  float dg = CSC * (dacp[e] * bb0 + dacp[25+(e)] * bb1 + \
                    dacp[50+(e)] * bb2 + dacp[75+(e)] * bb3); \
  y##e = dg * (1.0f - t2 * t2); a##e = dg; }
#define K3SEF(e,f) s = fmaf(y##f, W2p[(e)*WROW+(f)], s);
#define K3SE(e) { float s = a##e; RB(K3SEF, e) a##e = s; }
#define K3G1(e) y##e = a##e * (1.0f - t##e * t##e);
#define K3SFF(e,f) s = fmaf(y##f, W1p[(e)*WROW+(f)], s);
#define K3SF(e) { float s = a##e; RB(K3SFF, e) float h0e = x##e - t##e; \
  dsum = fmaf(s * (1.0f - h0e * h0e), W0p[e], dsum); }

// K3: per atom (block) x neighbor (thread): embed fwd + VJP -> dE -> forces.
__global__ __launch_bounds__(256, 2) void k_bwd_force(
    const float* __restrict__ dR, const int* __restrict__ neigh,
    const float* __restrict__ davg, const float* __restrict__ dstd,
    const float* __restrict__ eW0, const float* __restrict__ eb0,
    const float* __restrict__ eW1, const float* __restrict__ eb1,
    const float* __restrict__ eW2, const float* __restrict__ eb2,
    const float* __restrict__ dacc_ws, float* __restrict__ out) {
  __shared__ float sW1[2][D_ * WROW];
  __shared__ float sW2[2][D_ * WROW];
  __shared__ float sWb[2][4 * WROW];
  __shared__ float sDac[100];
  __shared__ float sF[3];
  int atom = blockIdx.x;
  int bb = atom >> 10;
  int n = atom & (N_ - 1);
  int t = (n >= 512) ? 1 : 0;
  int m = threadIdx.x;
  if (m < 3) sF[m] = 0.0f;
  stage_weights(t, m, eW0, eb0, eW1, eb1, eW2, eb2, sW1, sW2, sWb);
  if (m < 100) sDac[m] = dacc_ws[atom * 100 + m];
  int base = atom * M_ + m;
  float dx = dR[base * 3 + 0];
  float dy = dR[base * 3 + 1];
  float dz = dR[base * 3 + 2];
  int nb = neigh[base];
  float bb0, bb1, bb2, bb3;
  geom_blk(dx, dy, dz, nb, t, m, davg, dstd, bb0, bb1, bb2, bb3);
  __syncthreads();
  int half = m >> 7;
  const float* W1p = &sW1[half][0];
  const float* W2p = &sW2[half][0];
  const float* W0p = &sWb[half][0];
  const float* b0p = W0p + WROW;
  const float* b1p = W0p + 2 * WROW;
  const float* b2p = W0p + 3 * WROW;
  const float* dacp = sDac;
  float s0 = bb0;
  RA(K3H0)                 // x = h0
  RA(K3A1)                 // a = b1
  RA(K3M1R)                // a += h0 @ W1
  RA(K3T1)                 // t = tanh(a); x = h1
  RA(K3A2)                 // a = b2
  RA(K3M2R)                // a += h1 @ W2
  RA(K3DY)
  float db0 = 0.0f, db1 = 0.0f, db2 = 0.0f, db3 = 0.0f;
  RA(K3SD)                 // dblk accum; a := dG; y := g2
  RA(K3SE)                 // a := dh1 = dG + g2 @ W2^T
  RA(K3G1)                 // y := g1
  float dsum = 0.0f;
  RA(K3SF)                 // dsum = sum (dh0 gate) * W0
  float dE0 = db0 * CSC + dsum;
  float dE1 = db1 * CSC;
  float dE2 = db2 * CSC;
  float dE3 = db3 * CSC;
  float px, py, pz;
  geom_force(dx, dy, dz, nb, t, m, dstd, dE0, dE1, dE2, dE3, px, py, pz);
  // wave-level reduce for self-force, then one LDS atomic per wave
  float rx = px, ry = py, rz = pz;
#pragma unroll
  for (int off = 32; off > 0; off >>= 1) {
    rx += __shfl_down(rx, off, 64);
    ry += __shfl_down(ry, off, 64);
    rz += __shfl_down(rz, off, 64);
  }
  if ((m & 63) == 0) {
    atomicAdd(&sF[0], rx);
    atomicAdd(&sF[1], ry);
    atomicAdd(&sF[2], rz);
  }
  if (nb > 0) {  // scatter to neighbor j = nb-1
    int jn = nb - 1;
    int fi = 8 + NATOM + (bb * N_ + jn) * 3;
    atomicAdd(&out[fi + 0], px);
    atomicAdd(&out[fi + 1], py);
    atomicAdd(&out[fi + 2], pz);
  }
  __syncthreads();
  if (m < 3) atomicAdd(&out[8 + NATOM + atom * 3 + m], -sF[m]);
}

}  // namespace

extern "C" void kernel_launch(void* const* d_in, const int* in_sizes, int n_in,
                              void* d_out, int out_size, void* d_ws, size_t ws_size,
                              hipStream_t stream) {
  (void)in_sizes; (void)n_in; (void)ws_size;
  const float* image_dR   = (const float*)d_in[0];
  const int*   list_neigh = (const int*)d_in[1];
  const float* davg       = (const float*)d_in[2];
  const float* dstd       = (const float*)d_in[3];
  const float* eW0        = (const float*)d_in[4];
  const float* eb0        = (const float*)d_in[5];
  const float* eW1        = (const float*)d_in[6];
  const float* eb1        = (const float*)d_in[7];
  const float* eW2        = (const float*)d_in[8];
  const float* eb2        = (const float*)d_in[9];
  const float* fW0        = (const float*)d_in[10];
  const float* fb0        = (const float*)d_in[11];
  const float* fW1        = (const float*)d_in[12];
  const float* fb1        = (const float*)d_in[13];
  const float* fW2        = (const float*)d_in[14];
  const float* fb2        = (const float*)d_in[15];
  const float* fW3        = (const float*)d_in[16];
  const float* fb3        = (const float*)d_in[17];
  const float* ener_shift = (const float*)d_in[18];
  float* out = (float*)d_out;
  float* acc_ws  = (float*)d_ws;                  // 8192*100 floats
  float* dacc_ws = acc_ws + NATOM * 100;          // 8192*100 floats

  hipMemsetAsync(d_out, 0, (size_t)out_size * sizeof(float), stream);
  k_embed_acc<<<NATOM, 256, 0, stream>>>(image_dR, list_neigh, davg, dstd,
                                         eW0, eb0, eW1, eb1, eW2, eb2, acc_ws);
  k_fit<<<NATOM / 8, 256, 0, stream>>>(acc_ws, fW0, fb0, fW1, fb1, fW2, fb2,
                                       fW3, fb3, ener_shift, dacc_ws, out);
  k_bwd_force<<<NATOM, 256, 0, stream>>>(image_dR, list_neigh, davg, dstd,
                                         eW0, eb0, eW1, eb1, eW2, eb2,
                                         dacc_ws, out);
}

// Round 7
// 1107.074 us; speedup vs baseline: 5.7628x; 5.7628x over previous
//
#include <hip/hip_runtime.h>

#define DEV __device__ __forceinline__

typedef short bf16x8 __attribute__((ext_vector_type(8)));
typedef float floatx4 __attribute__((ext_vector_type(4)));

// ---- repetition macros ----
#define RC(F) F(0,0) F(0,1) F(1,0) F(1,1) F(2,0) F(2,1) F(3,0) F(3,1)
#define R4(F) F(0) F(1) F(2) F(3)
#define AP8(F) F(0) F(1) F(2) F(3) F(4) F(5) F(6) F(7)

namespace {

constexpr int B_ = 8;
constexpr int N_ = 1024;
constexpr int M_ = 256;
constexpr int D_ = 25;
constexpr int FH_ = 240;
constexpr int NATOM = B_ * N_;          // 8192
constexpr float CSC = 1.0f / 256.0f;    // 4/(NN*NTYPES*4)
constexpr int XP = 40;                  // X row pitch (bf16 elems): 80B rows, 20-bank stride

DEV float fast_tanh(float x) {
  float ax = fabsf(x);
  float e = __expf(-2.0f * ax);
  float r = (1.0f - e) * __builtin_amdgcn_rcpf(1.0f + e);
  return copysignf(r, x);
}

DEV short f2bf(float f) {  // fp32 -> bf16 RNE
  unsigned u = __builtin_bit_cast(unsigned, f);
  unsigned r = (u + 0x7FFFu + ((u >> 16) & 1u)) >> 16;
  return (short)r;
}

DEV floatx4 mm16(bf16x8 a, bf16x8 b, floatx4 c) {
  return __builtin_amdgcn_mfma_f32_16x16x32_bf16(a, b, c, 0, 0, 0);
}

// Normalized descriptor channels (pure scalars).
DEV void geom_blk(float dx, float dy, float dz, int nb, int t, int m,
                  const float* __restrict__ davg, const float* __restrict__ dstd,
                  float& o0, float& o1, float& o2, float& o3) {
  float mf = (nb > 0) ? 1.0f : 0.0f;
  float dr2 = dx * dx + dy * dy + dz * dz;
  float safe = (nb > 0) ? dr2 : 1.0f;
  float rs = __builtin_amdgcn_rsqf(safe);
  float rij = safe * rs;
  float inr = mf * rs;
  float x = rij * mf;
  float inr2 = inr * inr;
  float u = (x - 5.8f) * 5.0f;
  float uu = u * u;
  float A = -6.0f * uu + 15.0f * u - 10.0f;
  float poly = uu * u * A + 1.0f;
  bool mid = (x >= 5.8f) && (x < 6.0f);
  float vv = ((x < 5.8f) ? 1.0f : (mid ? poly : 0.0f)) * mf;
  int bidx = (t * M_ + m) * 4;
  float4 av = *(const float4*)(davg + bidx);
  float4 sv = *(const float4*)(dstd + bidx);
  o0 = (inr * vv - av.x) * __builtin_amdgcn_rcpf(sv.x);
  o1 = (dx * inr2 * vv - av.y) * __builtin_amdgcn_rcpf(sv.y);
  o2 = (dy * inr2 * vv - av.z) * __builtin_amdgcn_rcpf(sv.z);
  o3 = (dz * inr2 * vv - av.w) * __builtin_amdgcn_rcpf(sv.w);
}

// Jacobian folded into the force projection.
DEV void geom_force(float dx, float dy, float dz, int nb, int t, int m,
                    const float* __restrict__ dstd,
                    float dE0, float dE1, float dE2, float dE3,
                    float& px, float& py, float& pz) {
  float mf = (nb > 0) ? 1.0f : 0.0f;
  float dr2 = dx * dx + dy * dy + dz * dz;
  float safe = (nb > 0) ? dr2 : 1.0f;
  float rs = __builtin_amdgcn_rsqf(safe);
  float rij = safe * rs;
  float inr = mf * rs;
  float x = rij * mf;
  float inr2 = inr * inr;
  float inr4 = inr2 * inr2;
  float inr3 = inr4 * x;
  float u = (x - 5.8f) * 5.0f;
  float uu = u * u;
  float A = -6.0f * uu + 15.0f * u - 10.0f;
  float poly = uu * u * A + 1.0f;
  float dpoly = (3.0f * uu * A + uu * u * (-12.0f * u + 15.0f)) * 5.0f;
  bool mid = (x >= 5.8f) && (x < 6.0f);
  float vv = ((x < 5.8f) ? 1.0f : (mid ? poly : 0.0f)) * mf;
  float dvv = (mid ? dpoly : 0.0f) * mf;
  int bidx = (t * M_ + m) * 4;
  float4 sv = *(const float4*)(dstd + bidx);
  float e0 = dE0 * mf * __builtin_amdgcn_rcpf(sv.x);
  float e1 = dE1 * mf * __builtin_amdgcn_rcpf(sv.y);
  float e2 = dE2 * mf * __builtin_amdgcn_rcpf(sv.z);
  float e3 = dE3 * mf * __builtin_amdgcn_rcpf(sv.w);
  float ci = dvv * inr;
  float comx = ci * dx, comy = ci * dy, comz = ci * dz;
  float iv = inr3 * vv;
  float pre0 = inr, pre1 = dx * inr2, pre2 = dy * inr2, pre3 = dz * inr2;
  float txx = 2.0f * dx * dx * inr4 - inr2;
  float tyy = 2.0f * dy * dy * inr4 - inr2;
  float tzz = 2.0f * dz * dz * inr4 - inr2;
  float txy = 2.0f * dx * dy * inr4;
  float txz = 2.0f * dx * dz * inr4;
  float tyz = 2.0f * dy * dz * inr4;
  px = e0 * (dx * iv - pre0 * comx) + e1 * (txx * vv - pre1 * comx) +
       e2 * (txy * vv - pre2 * comx) + e3 * (txz * vv - pre3 * comx);
  py = e0 * (dy * iv - pre0 * comy) + e1 * (txy * vv - pre1 * comy) +
       e2 * (tyy * vv - pre2 * comy) + e3 * (tyz * vv - pre3 * comy);
  pz = e0 * (dz * iv - pre0 * comz) + e1 * (txz * vv - pre1 * comz) +
       e2 * (tyz * vv - pre2 * comz) + e3 * (tzz * vv - pre3 * comz);
}

// Stage embedding weights as bf16 B-operand matrices into LDS.
// Layout sWB[half][mat][n(32)][k(32)], zero-padded beyond 25.
// mat0: B=W1   -> store[n][k] = eW1[p, k, n]   (fwd mm1, transposed copy)
// mat1: B=W2   -> store[n][k] = eW2[p, k, n]   (fwd mm2)
// mat2: B=W2^T -> store[n][k] = eW2[p, n, k]   (bwd mm3, direct copy)
// mat3: B=W1^T -> store[n][k] = eW1[p, n, k]   (bwd mm4)
template <int NMAT>
DEV void stage_wb(int t, int tid, const float* __restrict__ eW1,
                  const float* __restrict__ eW2, short* __restrict__ sWB) {
  for (int idx = tid; idx < 2 * NMAT * 1024; idx += 256) {
    int h = idx / (NMAT * 1024);
    int rem = idx - h * (NMAT * 1024);
    int mat = rem >> 10;
    int nn = (rem >> 5) & 31;
    int kk = rem & 31;
    int p = t * 2 + h;
    float v = 0.0f;
    if (nn < 25 && kk < 25) {
      if (mat == 0)      v = eW1[p * 625 + kk * 25 + nn];
      else if (mat == 1) v = eW2[p * 625 + kk * 25 + nn];
      else if (mat == 2) v = eW2[p * 625 + nn * 25 + kk];
      else               v = eW1[p * 625 + nn * 25 + kk];
    }
    sWB[idx] = f2bf(v);
  }
}

// sB[half*100 + which*25 + e], which: 0=W0 1=b0 2=b1 3=b2
DEV void stage_b(int t, int tid, const float* __restrict__ eW0,
                 const float* __restrict__ eb0, const float* __restrict__ eb1,
                 const float* __restrict__ eb2, float* __restrict__ sB) {
  if (tid < 200) {
    int h = tid / 100;
    int r2 = tid - h * 100;
    int which = r2 / 25, e = r2 - which * 25;
    int p = t * 2 + h;
    float v = (which == 0) ? eW0[p * 25 + e]
            : (which == 1) ? eb0[p * 25 + e]
            : (which == 2) ? eb1[p * 25 + e] : eb2[p * 25 + e];
    sB[tid] = v;
  }
}

// ---- shared MFMA-phase macros ----
// D-layout: m = mrow + r, e = ct*16 + lid  (mfma_f32_16x16x32 C/D: col=lane&15,
// row=quad*4+reg [m89]); A-layout: A[m=lane&15][k=quad*8+j] [m120].
#define XW(r, ct, val) sX[(mrow + (r)) * XP + (ct) * 16 + lid] = f2bf(val);
#define H0C(r, ct) float h0_##r##_##ct = fast_tanh(fmaf(bk##r.x, W0f##ct, b0f##ct)); \
  XW(r, ct, h0_##r##_##ct)
#define T1C(r, ct) float t1_##r##_##ct = fast_tanh(Dc##ct[r] + b1f##ct); \
  float h1_##r##_##ct = h0_##r##_##ct + t1_##r##_##ct; XW(r, ct, h1_##r##_##ct)
#define BF4(v) v += __shfl_xor(v, 1); v += __shfl_xor(v, 2); \
  v += __shfl_xor(v, 4); v += __shfl_xor(v, 8);
#define PR2(v) v += __shfl_xor(v, 16); v += __shfl_xor(v, 32);
#define LDB(name, mat) \
  bf16x8 name##0 = *(const bf16x8*)&sWB[((half * NMATK + (mat)) * 32 + lid) * 32 + quad * 8]; \
  bf16x8 name##1 = *(const bf16x8*)&sWB[((half * NMATK + (mat)) * 32 + 16 + lid) * 32 + quad * 8];

// K1: per-atom block. Geometry -> MFMA embedding fwd -> acc[4][25].
__global__ __launch_bounds__(256, 3) void k_embed_acc(
    const float* __restrict__ dR, const int* __restrict__ neigh,
    const float* __restrict__ davg, const float* __restrict__ dstd,
    const float* __restrict__ eW0, const float* __restrict__ eb0,
    const float* __restrict__ eW1, const float* __restrict__ eb1,
    const float* __restrict__ eW2, const float* __restrict__ eb2,
    float* __restrict__ acc_ws) {
  __shared__ short sX[M_ * XP];
  __shared__ short sWB[2 * 2 * 1024];
  __shared__ float sB[200];
  __shared__ float4 sBlk4[M_];
  __shared__ float sWacc[4][4][32];
  int atom = blockIdx.x;
  int n = atom & (N_ - 1);
  int t = (n >= 512) ? 1 : 0;
  int tid = threadIdx.x;
  stage_wb<2>(t, tid, eW1, eW2, sWB);
  stage_b(t, tid, eW0, eb0, eb1, eb2, sB);
  {
    int base = atom * M_ + tid;
    float dx = dR[base * 3 + 0], dy = dR[base * 3 + 1], dz = dR[base * 3 + 2];
    int nb = neigh[base];
    float g0, g1, g2, g3;
    geom_blk(dx, dy, dz, nb, t, tid, davg, dstd, g0, g1, g2, g3);
    sBlk4[tid] = make_float4(g0, g1, g2, g3);
  }
  __syncthreads();
  const int NMATK = 2;
  int lane = tid & 63, w = tid >> 6, quad = lane >> 4, lid = lane & 15;
  int half = w >> 1;
  int e1i = 16 + lid;
  bool ev1 = (e1i < 25);
  const float* Bh = sB + half * 100;
  float W0f0 = Bh[lid];        float W0f1 = ev1 ? Bh[e1i] : 0.0f;
  float b0f0 = Bh[25 + lid];   float b0f1 = ev1 ? Bh[25 + e1i] : 0.0f;
  float b1f0 = Bh[50 + lid];   float b1f1 = ev1 ? Bh[50 + e1i] : 0.0f;
  float b2f0 = Bh[75 + lid];   float b2f1 = ev1 ? Bh[75 + e1i] : 0.0f;
  LDB(BW1T, 0) LDB(BW2T, 1)
  floatx4 Z4 = {0.0f, 0.0f, 0.0f, 0.0f};
  float pa00 = 0, pa01 = 0, pa10 = 0, pa11 = 0,
        pa20 = 0, pa21 = 0, pa30 = 0, pa31 = 0;
#define GAC(r, ct) { float G = h1_##r##_##ct + fast_tanh(Dc##ct[r] + b2f##ct); \
    pa0##ct = fmaf(bk##r.x, G, pa0##ct); pa1##ct = fmaf(bk##r.y, G, pa1##ct); \
    pa2##ct = fmaf(bk##r.z, G, pa2##ct); pa3##ct = fmaf(bk##r.w, G, pa3##ct); }
  for (int rt = 0; rt < 4; ++rt) {
    int rowbase = ((w << 2) + rt) << 4;
    int mrow = rowbase + (quad << 2);
    float4 bk0 = sBlk4[mrow + 0];
    float4 bk1 = sBlk4[mrow + 1];
    float4 bk2 = sBlk4[mrow + 2];
    float4 bk3 = sBlk4[mrow + 3];
    RC(H0C)
    const bf16x8* ap = (const bf16x8*)&sX[(rowbase + lid) * XP + quad * 8];
    bf16x8 af = *ap;
    floatx4 Dc0 = mm16(af, BW1T0, Z4);
    floatx4 Dc1 = mm16(af, BW1T1, Z4);
    RC(T1C)
    af = *ap;
    Dc0 = mm16(af, BW2T0, Z4);
    Dc1 = mm16(af, BW2T1, Z4);
    RC(GAC)
  }
  PR2(pa00) PR2(pa01) PR2(pa10) PR2(pa11)
  PR2(pa20) PR2(pa21) PR2(pa30) PR2(pa31)
  if (lane < 16) {
    sWacc[w][0][lid] = pa00; sWacc[w][1][lid] = pa10;
    sWacc[w][2][lid] = pa20; sWacc[w][3][lid] = pa30;
    if (ev1) {
      sWacc[w][0][e1i] = pa01; sWacc[w][1][e1i] = pa11;
      sWacc[w][2][e1i] = pa21; sWacc[w][3][e1i] = pa31;
    }
  }
  __syncthreads();
  if (tid < 100) {
    int d = tid / 25, e = tid - d * 25;
    float s = sWacc[0][d][e] + sWacc[1][d][e] + sWacc[2][d][e] + sWacc[3][d][e];
    acc_ws[atom * 100 + tid] = s * CSC;
  }
}

// ---- K2 (unchanged from R5, passing) ----
#define DECL8(v) float c0=(v),c1=(v),c2=(v),c3=(v),c4=(v),c5=(v),c6=(v),c7=(v);
#define F8X(q)  c##q = fmaf(sXf[q][i], wv, c##q);
#define F8H0(q) c##q = fmaf(sH0[q][f], wv, c##q);
#define F8H1(q) c##q = fmaf(sH1[q][f], wv, c##q);
#define F8T2(q) c##q = fmaf(sT2[q][k], wv, c##q);
#define F8T1(q) c##q = fmaf(sT1[q][k], wv, c##q);
#define F8G0(q) c##q = fmaf(sH0[q][jj], wv, c##q);
#define L0S(q) sH0[q][j] = fast_tanh(c##q);
#define L1S(q) { float tv = fast_tanh(c##q); sT1[q][j] = tv; sH1[q][j] = sH0[q][j] + tv; }
#define L2S(q) { float tv = fast_tanh(c##q); sT2[q][j] = tv; atomicAdd(&sEi[q], (sH1[q][j] + tv) * w3); }
#define G2S(q) { float tv = sT2[q][j]; sT2[q][j] = w3 * (1.0f - tv * tv); }
#define D1S(q) { float dh1 = c##q; float tv = sT1[q][j]; sH1[q][j] = dh1; sT1[q][j] = dh1 * (1.0f - tv * tv); }
#define D0S(q) { float h0v = sH0[q][j]; sH0[q][j] = c##q * (1.0f - h0v * h0v); }
#define DXS(q) sXf[q][i] = c##q;

__global__ __launch_bounds__(256, 4) void k_fit(
    const float* __restrict__ acc_ws,
    const float* __restrict__ fW0, const float* __restrict__ fb0,
    const float* __restrict__ fW1, const float* __restrict__ fb1,
    const float* __restrict__ fW2, const float* __restrict__ fb2,
    const float* __restrict__ fW3, const float* __restrict__ fb3,
    const float* __restrict__ ener_shift,
    float* __restrict__ dacc_ws, float* __restrict__ out) {
  constexpr int AB = 8;
  __shared__ float sAcc[AB][100];
  __shared__ float sXf[AB][400];
  __shared__ float sH0[AB][FH_];
  __shared__ float sT1[AB][FH_];
  __shared__ float sH1[AB][FH_];
  __shared__ float sT2[AB][FH_];
  __shared__ float sEi[AB];
  int a0 = blockIdx.x * AB;
  int bb = a0 >> 10;
  int n0 = a0 & (N_ - 1);
  int t = (n0 >= 512) ? 1 : 0;
  int tid = threadIdx.x;
  for (int idx = tid; idx < AB * 100; idx += 256)
    ((float*)sAcc)[idx] = acc_ws[a0 * 100 + idx];
  if (tid < AB) sEi[tid] = 0.0f;
  __syncthreads();
  for (int idx = tid; idx < AB * 400; idx += 256) {
    int a = idx / 400; int r = idx % 400; int e = r >> 4; int f = r & 15;
    const float* A = sAcc[a];
    sXf[a][r] = A[e] * A[f] + A[25 + e] * A[25 + f] + A[50 + e] * A[50 + f] +
                A[75 + e] * A[75 + f];
  }
  __syncthreads();
  const float* W0 = fW0 + t * 400 * FH_;
  const float* W1 = fW1 + t * FH_ * FH_;
  const float* W2 = fW2 + t * FH_ * FH_;
  const float* B0 = fb0 + t * FH_;
  const float* B1 = fb1 + t * FH_;
  const float* B2 = fb2 + t * FH_;
  const float* W3 = fW3 + t * FH_;
  int j = tid;
  if (j < FH_) {
    DECL8(B0[j])
    for (int i = 0; i < 400; ++i) { float wv = W0[i * FH_ + j]; AP8(F8X) }
    AP8(L0S)
  }
  __syncthreads();
  if (j < FH_) {
    DECL8(B1[j])
    for (int f = 0; f < FH_; ++f) { float wv = W1[f * FH_ + j]; AP8(F8H0) }
    AP8(L1S)
  }
  __syncthreads();
  if (j < FH_) {
    DECL8(B2[j])
    for (int f = 0; f < FH_; ++f) { float wv = W2[f * FH_ + j]; AP8(F8H1) }
    float w3 = W3[j];
    AP8(L2S)
  }
  __syncthreads();
  if (tid < AB) {
    float ei = sEi[tid] + fb3[t] + ener_shift[t];
    out[8 + a0 + tid] = ei;
    sEi[tid] = ei;
  }
  if (j < FH_) {
    float w3 = W3[j];
    AP8(G2S)
  }
  __syncthreads();
  if (tid == 0) {
    float s = sEi[0] + sEi[1] + sEi[2] + sEi[3] + sEi[4] + sEi[5] + sEi[6] + sEi[7];
    atomicAdd(&out[bb], s);
  }
  if (j < FH_) {
    DECL8(W3[j])
    for (int k = 0; k < FH_; ++k) { float wv = W2[j * FH_ + k]; AP8(F8T2) }
    AP8(D1S)
  }
  __syncthreads();
  if (j < FH_) {
    DECL8(sH1[0][j])
    c1 = sH1[1][j]; c2 = sH1[2][j]; c3 = sH1[3][j];
    c4 = sH1[4][j]; c5 = sH1[5][j]; c6 = sH1[6][j]; c7 = sH1[7][j];
    for (int k = 0; k < FH_; ++k) { float wv = W1[j * FH_ + k]; AP8(F8T1) }
    AP8(D0S)
  }
  __syncthreads();
  for (int i = tid; i < 400; i += 256) {
    DECL8(0.0f)
    for (int jj = 0; jj < FH_; ++jj) { float wv = W0[i * FH_ + jj]; AP8(F8G0) }
    AP8(DXS)
  }
  __syncthreads();
  for (int idx = tid; idx < AB * 100; idx += 256) {
    int a = idx / 100; int r = idx % 100; int d = r / 25; int e = r % 25;
    const float* A = sAcc[a];
    const float* DX = sXf[a];
    float sum = 0.0f;
#pragma unroll
    for (int f = 0; f < 16; ++f) sum = fmaf(DX[e * 16 + f], A[d * 25 + f], sum);
    if (e < 16) {
#pragma unroll
      for (int e2 = 0; e2 < 25; ++e2) sum = fmaf(DX[e2 * 16 + e], A[d * 25 + e2], sum);
    }
    dacc_ws[a0 * 100 + idx] = sum;
  }
}

// K3: per-atom block. MFMA embedding fwd + VJP -> dE -> forces.
__global__ __launch_bounds__(256, 2) void k_bwd_force(
    const float* __restrict__ dR, const int* __restrict__ neigh,
    const float* __restrict__ davg, const float* __restrict__ dstd,
    const float* __restrict__ eW0, const float* __restrict__ eb0,
    const float* __restrict__ eW1, const float* __restrict__ eb1,
    const float* __restrict__ eW2, const float* __restrict__ eb2,
    const float* __restrict__ dacc_ws, float* __restrict__ out) {
  __shared__ short sX[M_ * XP];
  __shared__ short sWB[2 * 4 * 1024];
  __shared__ float sB[200];
  __shared__ float sDacc[100];
  __shared__ float4 sBlk4[M_];
  __shared__ float4 sDE4[M_];
  __shared__ float sF[3];
  int atom = blockIdx.x;
  int bbx = atom >> 10;
  int n = atom & (N_ - 1);
  int t = (n >= 512) ? 1 : 0;
  int tid = threadIdx.x;
  if (tid < 3) sF[tid] = 0.0f;
  stage_wb<4>(t, tid, eW1, eW2, sWB);
  stage_b(t, tid, eW0, eb0, eb1, eb2, sB);
  if (tid < 100) sDacc[tid] = dacc_ws[atom * 100 + tid];
  int base = atom * M_ + tid;
  float dxv = dR[base * 3 + 0], dyv = dR[base * 3 + 1], dzv = dR[base * 3 + 2];
  int nbv = neigh[base];
  {
    float g0, g1, g2, g3;
    geom_blk(dxv, dyv, dzv, nbv, t, tid, davg, dstd, g0, g1, g2, g3);
    sBlk4[tid] = make_float4(g0, g1, g2, g3);
  }
  __syncthreads();
  const int NMATK = 4;
  int lane = tid & 63, w = tid >> 6, quad = lane >> 4, lid = lane & 15;
  int half = w >> 1;
  int e1i = 16 + lid;
  bool ev1 = (e1i < 25);
  const float* Bh = sB + half * 100;
  float W0f0 = Bh[lid];        float W0f1 = ev1 ? Bh[e1i] : 0.0f;
  float b0f0 = Bh[25 + lid];   float b0f1 = ev1 ? Bh[25 + e1i] : 0.0f;
  float b1f0 = Bh[50 + lid];   float b1f1 = ev1 ? Bh[50 + e1i] : 0.0f;
  float b2f0 = Bh[75 + lid];   float b2f1 = ev1 ? Bh[75 + e1i] : 0.0f;
  float da00 = sDacc[lid];      float da01 = ev1 ? sDacc[e1i] : 0.0f;
  float da10 = sDacc[25 + lid]; float da11 = ev1 ? sDacc[25 + e1i] : 0.0f;
  float da20 = sDacc[50 + lid]; float da21 = ev1 ? sDacc[50 + e1i] : 0.0f;
  float da30 = sDacc[75 + lid]; float da31 = ev1 ? sDacc[75 + e1i] : 0.0f;
  LDB(BW1T, 0) LDB(BW2T, 1) LDB(BW2B, 2) LDB(BW1B, 3)
  floatx4 Z4 = {0.0f, 0.0f, 0.0f, 0.0f};
#define T2C(r, ct) float t2_##r##_##ct = fast_tanh(Dc##ct[r] + b2f##ct); \
    float G_##r##_##ct = h1_##r##_##ct + t2_##r##_##ct; \
    float dG_##r##_##ct = CSC * (da0##ct * bk##r.x + da1##ct * bk##r.y + \
                                 da2##ct * bk##r.z + da3##ct * bk##r.w); \
    XW(r, ct, dG_##r##_##ct * (1.0f - t2_##r##_##ct * t2_##r##_##ct))
#define DBLK(r) \
    float db_##r##_0 = da00 * G_##r##_0 + da01 * G_##r##_1; \
    float db_##r##_1 = da10 * G_##r##_0 + da11 * G_##r##_1; \
    float db_##r##_2 = da20 * G_##r##_0 + da21 * G_##r##_1; \
    float db_##r##_3 = da30 * G_##r##_0 + da31 * G_##r##_1;
#define DBR(r) BF4(db_##r##_0) BF4(db_##r##_1) BF4(db_##r##_2) BF4(db_##r##_3)
#define DH1C(r, ct) float dh1_##r##_##ct = dG_##r##_##ct + Dc##ct[r]; \
    XW(r, ct, dh1_##r##_##ct * (1.0f - t1_##r##_##ct * t1_##r##_##ct))
#define DSC(r) float dh0_##r##_0 = dh1_##r##_0 + Dc0[r]; \
    float dh0_##r##_1 = dh1_##r##_1 + Dc1[r]; \
    float ds_##r = dh0_##r##_0 * (1.0f - h0_##r##_0 * h0_##r##_0) * W0f0 \
                 + dh0_##r##_1 * (1.0f - h0_##r##_1 * h0_##r##_1) * W0f1; \
    BF4(ds_##r)
  for (int rt = 0; rt < 4; ++rt) {
    int rowbase = ((w << 2) + rt) << 4;
    int mrow = rowbase + (quad << 2);
    float4 bk0 = sBlk4[mrow + 0];
    float4 bk1 = sBlk4[mrow + 1];
    float4 bk2 = sBlk4[mrow + 2];
    float4 bk3 = sBlk4[mrow + 3];
    RC(H0C)
    const bf16x8* ap = (const bf16x8*)&sX[(rowbase + lid) * XP + quad * 8];
    bf16x8 af = *ap;
    floatx4 Dc0 = mm16(af, BW1T0, Z4);
    floatx4 Dc1 = mm16(af, BW1T1, Z4);
    RC(T1C)
    af = *ap;
    Dc0 = mm16(af, BW2T0, Z4);
    Dc1 = mm16(af, BW2T1, Z4);
    RC(T2C)
    R4(DBLK)
    R4(DBR)
    af = *ap;               // g2
    Dc0 = mm16(af, BW2B0, Z4);
    Dc1 = mm16(af, BW2B1, Z4);
    RC(DH1C)
    af = *ap;               // g1
    Dc0 = mm16(af, BW1B0, Z4);
    Dc1 = mm16(af, BW1B1, Z4);
    R4(DSC)
    if (lid == 0) {
      sDE4[mrow + 0] = make_float4(db_0_0 * CSC + ds_0, db_0_1 * CSC, db_0_2 * CSC, db_0_3 * CSC);
      sDE4[mrow + 1] = make_float4(db_1_0 * CSC + ds_1, db_1_1 * CSC, db_1_2 * CSC, db_1_3 * CSC);
      sDE4[mrow + 2] = make_float4(db_2_0 * CSC + ds_2, db_2_1 * CSC, db_2_2 * CSC, db_2_3 * CSC);
      sDE4[mrow + 3] = make_float4(db_3_0 * CSC + ds_3, db_3_1 * CSC, db_3_2 * CSC, db_3_3 * CSC);
    }
  }
  __syncthreads();
  // force tail: thread tid = neighbor m
  float4 dE = sDE4[tid];
  float px, py, pz;
  geom_force(dxv, dyv, dzv, nbv, t, tid, dstd, dE.x, dE.y, dE.z, dE.w, px, py, pz);
  float rx = px, ry = py, rz = pz;
#pragma unroll
  for (int off = 32; off > 0; off >>= 1) {
    rx += __shfl_down(rx, off, 64);
    ry += __shfl_down(ry, off, 64);
    rz += __shfl_down(rz, off, 64);
  }
  if ((tid & 63) == 0) {
    atomicAdd(&sF[0], rx);
    atomicAdd(&sF[1], ry);
    atomicAdd(&sF[2], rz);
  }
  if (nbv > 0) {
    int jn = nbv - 1;
    int fi = 8 + NATOM + (bbx * N_ + jn) * 3;
    atomicAdd(&out[fi + 0], px);
    atomicAdd(&out[fi + 1], py);
    atomicAdd(&out[fi + 2], pz);
  }
  __syncthreads();
  if (tid < 3) atomicAdd(&out[8 + NATOM + atom * 3 + tid], -sF[tid]);
}

}  // namespace

extern "C" void kernel_launch(void* const* d_in, const int* in_sizes, int n_in,
                              void* d_out, int out_size, void* d_ws, size_t ws_size,
                              hipStream_t stream) {
  (void)in_sizes; (void)n_in; (void)ws_size;
  const float* image_dR   = (const float*)d_in[0];
  const int*   list_neigh = (const int*)d_in[1];
  const float* davg       = (const float*)d_in[2];
  const float* dstd       = (const float*)d_in[3];
  const float* eW0        = (const float*)d_in[4];
  const float* eb0        = (const float*)d_in[5];
  const float* eW1        = (const float*)d_in[6];
  const float* eb1        = (const float*)d_in[7];
  const float* eW2        = (const float*)d_in[8];
  const float* eb2        = (const float*)d_in[9];
  const float* fW0        = (const float*)d_in[10];
  const float* fb0        = (const float*)d_in[11];
  const float* fW1        = (const float*)d_in[12];
  const float* fb1        = (const float*)d_in[13];
  const float* fW2        = (const float*)d_in[14];
  const float* fb2        = (const float*)d_in[15];
  const float* fW3        = (const float*)d_in[16];
  const float* fb3        = (const float*)d_in[17];
  const float* ener_shift = (const float*)d_in[18];
  float* out = (float*)d_out;
  float* acc_ws  = (float*)d_ws;                  // 8192*100 floats
  float* dacc_ws = acc_ws + NATOM * 100;          // 8192*100 floats

  hipMemsetAsync(d_out, 0, (size_t)out_size * sizeof(float), stream);
  k_embed_acc<<<NATOM, 256, 0, stream>>>(image_dR, list_neigh, davg, dstd,
                                         eW0, eb0, eW1, eb1, eW2, eb2, acc_ws);
  k_fit<<<NATOM / 8, 256, 0, stream>>>(acc_ws, fW0, fb0, fW1, fb1, fW2, fb2,
                                       fW3, fb3, ener_shift, dacc_ws, out);
  k_bwd_force<<<NATOM, 256, 0, stream>>>(image_dR, list_neigh, davg, dstd,
                                         eW0, eb0, eW1, eb1, eW2, eb2,
                                         dacc_ws, out);
}